// Round 11
// baseline (205.805 us; speedup 1.0000x reference)
//
#include <hip/hip_runtime.h>

// Problem constants (B=4, G=512, Dim=384, N=25088, img 224, kernel_size 8)
#define BATCH 4
#define NGRP  512
#define DIM   384
#define NPTS  25088
#define IMG   224
#define KS    8
#define HOUT  28
#define LIVE_HO 14        // pooled rows 0..13 live, 14..27 exactly zero

#define GB    8
#define NBIN  (GB * GB * GB)       // 512
#define NSLICE 8
#define SLICE (NPTS / NSLICE)      // 3136
#define CAP   192                  // per-wave candidate buffer (mean ~125, 6 sigma)
#define PSTRIDE 388                // psum row stride (floats)

// ---- workspace layout (bytes), per batch ----
#define WS_CB 0                          // float4 cbin[512]        8192
#define WS_CS 8192                       // int cstart[513]         2052 -> pad
#define WS_PS 10256                      // int pstart[8][513]     16416
#define WS_PB 26672                      // float4 pbin[25088]    401408
#define WS_BSTRIDE 428080
#define WS_PAIRS (BATCH * WS_BSTRIDE)    // int2 pairs[B*N*3] after batch blocks

__device__ __forceinline__ bool kvlt(float da, int ia, float db, int ib) {
    // strict total order on (d2, center idx) — lax.top_k stable-tie semantics
    return (da < db) || ((da == db) && (ia < ib));
}

// merge two sorted (d2,idx) triples -> sorted top-3 (R5 merge, proven R5-R7)
__device__ __forceinline__ void merge3(
    float& e0, int& j0, float& e1, int& j1, float& e2, int& j2,
    float f0, int g0, float f1, int g1, float f2, int g2)
{
    const bool c0 = kvlt(e0, j0, f0, g0);
    const float X0 = c0 ? e0 : f0;  const int U0 = c0 ? j0 : g0;
    const float X1 = c0 ? e1 : f1;  const int U1 = c0 ? j1 : g1;
    const float X2 = c0 ? e2 : f2;  const int U2 = c0 ? j2 : g2;
    const float Y0 = c0 ? f0 : e0;  const int V0 = c0 ? g0 : j0;
    const float Y1 = c0 ? f1 : e1;  const int V1 = c0 ? g1 : j1;
    const bool c1 = kvlt(X1, U1, Y0, V0);
    const float r1 = c1 ? X1 : Y0;  const int s1 = c1 ? U1 : V0;
    const bool c2a = kvlt(X2, U2, Y0, V0);
    const float r2a = c2a ? X2 : Y0; const int s2a = c2a ? U2 : V0;
    const bool c2b = kvlt(X1, U1, Y1, V1);
    const float r2b = c2b ? X1 : Y1; const int s2b = c2b ? U1 : V1;
    e0 = X0;  j0 = U0;
    e1 = r1;  j1 = s1;
    e2 = c1 ? r2a : r2b;
    j2 = c1 ? s2a : s2b;
}

__device__ __forceinline__ int bin_of(float v) {
    int i = (int)(v * 8.0f);             // *8 exact (pow2), inputs in [0,1)
    return min(max(i, 0), GB - 1);
}

// ===========================================================================
// Binning kernel, grid (9, BATCH) x 512 thr (unchanged from R10):
//   blockIdx.x == 8 : centers -> 8^3 CSR;  == s : point slice s -> CSR.
// Within-bin order nondeterministic (atomics) — harmless: selection is
// (d2,idx)-lex order-invariant.
// ===========================================================================
__global__ __launch_bounds__(512) void bin_kernel(
    const float* __restrict__ centers,   // (B, G, 3)
    const float* __restrict__ points,    // (B, N, 3)
    char* __restrict__ ws)
{
    const int role = blockIdx.x;         // 0..7 point slices, 8 = centers
    const int b    = blockIdx.y;
    const int t    = threadIdx.x;

    __shared__ int cnt[NBIN];
    __shared__ int cur[NBIN];
    __shared__ int sstart[NBIN];
    __shared__ int wsum[8];

    cnt[t] = 0; cur[t] = 0;
    __syncthreads();

    char* wb = ws + (size_t)b * WS_BSTRIDE;

    if (role == NSLICE) {
        const float x = centers[((size_t)b * NGRP + t) * 3 + 0];
        const float y = centers[((size_t)b * NGRP + t) * 3 + 1];
        const float z = centers[((size_t)b * NGRP + t) * 3 + 2];
        const int bin = (bin_of(z) * GB + bin_of(y)) * GB + bin_of(x);
        atomicAdd(&cnt[bin], 1);
        __syncthreads();

        const int lane = t & 63, wid = t >> 6;
        const int v = cnt[t];
        int inc = v;
        #pragma unroll
        for (int d = 1; d < 64; d <<= 1) {
            const int nv = __shfl_up(inc, d, 64);
            if (lane >= d) inc += nv;
        }
        if (lane == 63) wsum[wid] = inc;
        __syncthreads();
        if (t == 0) {
            int acc = 0;
            #pragma unroll
            for (int i = 0; i < 8; ++i) { const int c = wsum[i]; wsum[i] = acc; acc += c; }
        }
        __syncthreads();
        const int startv = wsum[wid] + inc - v;

        float4* cb4 = (float4*)(wb + WS_CB);
        int*    cs  = (int*)(wb + WS_CS);
        cs[t] = startv;
        if (t == 0) cs[NBIN] = NGRP;
        sstart[t] = startv;
        __syncthreads();
        const int pos = sstart[bin] + atomicAdd(&cur[bin], 1);
        cb4[pos] = make_float4(x, y, z, __int_as_float(t));
    } else {
        const int n0 = role * SLICE;
        const float* pb = points + ((size_t)b * NPTS + n0) * 3;
        for (int n = t; n < SLICE; n += 512) {
            const float x = pb[n * 3 + 0];
            const float y = pb[n * 3 + 1];
            const float z = pb[n * 3 + 2];
            const int bin = (bin_of(z) * GB + bin_of(y)) * GB + bin_of(x);
            atomicAdd(&cnt[bin], 1);
        }
        __syncthreads();

        const int lane = t & 63, wid = t >> 6;
        const int v = cnt[t];
        int inc = v;
        #pragma unroll
        for (int d = 1; d < 64; d <<= 1) {
            const int nv = __shfl_up(inc, d, 64);
            if (lane >= d) inc += nv;
        }
        if (lane == 63) wsum[wid] = inc;
        __syncthreads();
        if (t == 0) {
            int acc = 0;
            #pragma unroll
            for (int i = 0; i < 8; ++i) { const int c = wsum[i]; wsum[i] = acc; acc += c; }
        }
        __syncthreads();
        const int startv = wsum[wid] + inc - v;

        int* ps = (int*)(wb + WS_PS) + role * (NBIN + 1);
        ps[t] = n0 + startv;
        if (t == 0) ps[NBIN] = n0 + SLICE;
        sstart[t] = startv;
        __syncthreads();

        float4* pb4 = (float4*)(wb + WS_PB);
        for (int n = t; n < SLICE; n += 512) {
            const float x = pb[n * 3 + 0];
            const float y = pb[n * 3 + 1];
            const float z = pb[n * 3 + 2];
            const int bin = (bin_of(z) * GB + bin_of(y)) * GB + bin_of(x);
            const int pos = n0 + sstart[bin] + atomicAdd(&cur[bin], 1);
            pb4[pos] = make_float4(x, y, z, __int_as_float(n0 + n));
        }
    }
}

// ===========================================================================
// NN kernel: one WAVE per (batch, bin). R10 flatten, restructured for ILP:
//  - region is the ANCHORED 5x5x5 window x0=clamp(bx-2,0,3) etc. Domain
//    faces exclude no centers, so per-lane covered radius
//    r_cov = min(real-face distances) >= 0.25 everywhere (>=0.5 at corners)
//    -> fallback probability ~1e-9 (was ~0.2 at corners: the R10 serial
//    fallback waves set the 102us makespan).
//  - 4 interleaved top-3 states in the hot loop AND the fallback, merged by
//    the proven R5 merge -> 4 independent dependency chains.
//  - scalar (readfirstlane) loop bound + sentinel pad to x4 -> counted,
//    pipelineable loop over contiguous LDS broadcasts.
// Exactness: accept iff e2 < r_cov^2 - 1e-5 (unvisited formula-d2 >=
// true-d2 - 6e-7 >= r_cov^2 - 6e-7); failures + buffer overflow rescan all
// 512 with reset state. (d2,idx)-lex selection is order-invariant ->
// bit-identical to rounds 4..10.
// ===========================================================================
__global__ __launch_bounds__(256) void nn_kernel(
    const char* __restrict__ ws,
    int2* __restrict__ pairs_g)          // (B, N, 3) packed (idx, w bits)
{
    const int b = blockIdx.y;
    const int t = threadIdx.x;
    const int wid  = t >> 6;
    const int lane = t & 63;

    __shared__ float4 scb[NGRP];                 // centers x,y,z,as_float(idx)
    __shared__ int    scs[NBIN + 1];
    __shared__ float4 cand[4][CAP];              // per-wave candidates x,y,z,ss
    __shared__ int    candi[4][CAP];             // per-wave candidate idx

    const char* wb = ws + (size_t)b * WS_BSTRIDE;
    const float4* g4  = (const float4*)(wb + WS_CB);
    const int*    gs  = (const int*)(wb + WS_CS);
    const int*    gps = (const int*)(wb + WS_PS);
    const float4* pb4 = (const float4*)(wb + WS_PB);

    for (int i = t; i < NGRP; i += 256) scb[i] = g4[i];
    for (int i = t; i < NBIN + 1; i += 256) scs[i] = gs[i];
    __syncthreads();

    const int bin = blockIdx.x * 4 + wid;
    const int bx = bin & 7;
    const int by = (bin >> 3) & 7;
    const int bz = bin >> 6;

    // ---- this bin's points across the 8 slices (wave-uniform CSR reads) ----
    int base_s[NSLICE], cnt_s[NSLICE], pre_s[NSLICE];
    int npts = 0;
    #pragma unroll
    for (int s = 0; s < NSLICE; ++s) {
        const int a0 = gps[s * (NBIN + 1) + bin];
        const int a1 = gps[s * (NBIN + 1) + bin + 1];
        base_s[s] = a0;
        cnt_s[s]  = a1 - a0;
        pre_s[s]  = npts;
        npts += a1 - a0;
    }
    if (npts == 0) return;

    // ---- anchored 5x5x5 region -> contiguous LDS candidate buffer ----
    const int x0 = min(max(bx - 2, 0), GB - 5);
    const int y0 = min(max(by - 2, 0), GB - 5);
    const int z0 = min(max(bz - 2, 0), GB - 5);

    int segStart = 0, segLen = 0;
    if (lane < 25) {
        const int zz = z0 + lane / 5;
        const int yy = y0 + lane - (lane / 5) * 5;
        const int rowbase = (zz * GB + yy) * GB;
        segStart = scs[rowbase + x0];
        segLen   = scs[rowbase + x0 + 5] - segStart;
    }
    int pre = segLen;
    #pragma unroll
    for (int d = 1; d < 64; d <<= 1) {
        const int nv = __shfl_up(pre, d, 64);
        if (lane >= d) pre += nv;
    }
    const int dst   = pre - segLen;
    const int ncand = __shfl(pre, 24, 64);
    const bool overflow = (ncand > CAP - 4);

    if (!overflow) {
        if (lane < 25) {
            for (int k = 0; k < segLen; ++k) {
                const float4 cc = scb[segStart + k];
                const float ss = __fadd_rn(__fadd_rn(__fmul_rn(cc.x, cc.x),
                                                     __fmul_rn(cc.y, cc.y)),
                                           __fmul_rn(cc.z, cc.z));
                cand[wid][dst + k]  = make_float4(cc.x, cc.y, cc.z, ss);
                candi[wid][dst + k] = __float_as_int(cc.w);
            }
        }
        if (lane < 4) {   // sentinels (never selected) to pad to multiple of 4
            cand[wid][ncand + lane]  = make_float4(0.0f, 0.0f, 0.0f, 1e30f);
            candi[wid][ncand + lane] = 0x7fffffff;
        }
    }
    __threadfence_block();
    const int nc4 = __builtin_amdgcn_readfirstlane((ncand + 3) & ~3);

    // ---- per-axis real region faces (domain faces excluded) ----
    const float X0f = 0.125f * (float)x0, X1f = 0.125f * (float)(x0 + 5);
    const float Y0f = 0.125f * (float)y0, Y1f = 0.125f * (float)(y0 + 5);
    const float Z0f = 0.125f * (float)z0, Z1f = 0.125f * (float)(z0 + 5);

    // ---- process this bin's points, 64 per chunk ----
    for (int base = 0; base < npts; base += 64) {
        const int me = base + lane;
        const bool live = (me < npts);

        float px = 0.0f, py = 0.0f, pz = 0.0f, tn = 0.0f;
        int pid = 0;
        if (live) {
            int s = 0, rem = me;
            #pragma unroll
            for (int k = 0; k < NSLICE; ++k) {
                if (me >= pre_s[k] && cnt_s[k] > 0) { s = k; rem = me - pre_s[k]; }
            }
            const float4 p = pb4[base_s[s] + rem];
            px = p.x; py = p.y; pz = p.z;
            pid = __float_as_int(p.w);
            tn = __fadd_rn(__fadd_rn(__fmul_rn(px, px), __fmul_rn(py, py)),
                           __fmul_rn(pz, pz));
        }

        // 4 interleaved top-3 states over the candidate buffer
        float se0[4], se1[4], se2[4];
        int   sj0[4], sj1[4], sj2[4];
        #pragma unroll
        for (int u = 0; u < 4; ++u) {
            se0[u] = 1e30f; se1[u] = 1e30f; se2[u] = 1e30f;
            sj0[u] = 0;     sj1[u] = 0;     sj2[u] = 0;
        }

        if (!overflow) {
            for (int c = 0; c < nc4; c += 4) {
                #pragma unroll
                for (int u = 0; u < 4; ++u) {
                    const float4 cc = cand[wid][c + u];
                    const int sidx  = candi[wid][c + u];
                    float acc = __fmul_rn(px, cc.x);
                    acc = fmaf(py, cc.y, acc);
                    acc = fmaf(pz, cc.z, acc);
                    const float dd = __fsub_rn(__fadd_rn(tn, cc.w),
                                               __fmul_rn(2.0f, acc));
                    const bool lt2 = kvlt(dd, sidx, se2[u], sj2[u]);
                    const bool lt1 = kvlt(dd, sidx, se1[u], sj1[u]);
                    const bool lt0 = kvlt(dd, sidx, se0[u], sj0[u]);
                    se2[u] = lt1 ? se1[u] : (lt2 ? dd : se2[u]);
                    sj2[u] = lt1 ? sj1[u] : (lt2 ? sidx : sj2[u]);
                    se1[u] = lt0 ? se0[u] : (lt1 ? dd : se1[u]);
                    sj1[u] = lt0 ? sj0[u] : (lt1 ? sidx : sj1[u]);
                    se0[u] = lt0 ? dd : se0[u];
                    sj0[u] = lt0 ? sidx : sj0[u];
                }
            }
            merge3(se0[0], sj0[0], se1[0], sj1[0], se2[0], sj2[0],
                   se0[1], sj0[1], se1[1], sj1[1], se2[1], sj2[1]);
            merge3(se0[2], sj0[2], se1[2], sj1[2], se2[2], sj2[2],
                   se0[3], sj0[3], se1[3], sj1[3], se2[3], sj2[3]);
            merge3(se0[0], sj0[0], se1[0], sj1[0], se2[0], sj2[0],
                   se0[2], sj0[2], se1[2], sj1[2], se2[2], sj2[2]);
        }
        float e0 = se0[0], e1 = se1[0], e2 = se2[0];
        int   j0 = sj0[0], j1 = sj1[0], j2 = sj2[0];

        // ---- per-lane covered radius; accept or (rarely) full rescan ----
        float rc = 1e30f;
        if (x0 > 0) rc = fminf(rc, px - X0f);
        if (x0 < 3) rc = fminf(rc, X1f - px);
        if (y0 > 0) rc = fminf(rc, py - Y0f);
        if (y0 < 3) rc = fminf(rc, Y1f - py);
        if (z0 > 0) rc = fminf(rc, pz - Z0f);
        if (z0 < 3) rc = fminf(rc, Z1f - pz);
        const bool ok = !live || (!overflow && (e2 < rc * rc - 1e-5f));

        if (__any(!ok)) {
            const bool redo = !ok;
            float fe0[4], fe1[4], fe2[4];
            int   fj0[4], fj1[4], fj2[4];
            #pragma unroll
            for (int u = 0; u < 4; ++u) {
                fe0[u] = 1e30f; fe1[u] = 1e30f; fe2[u] = 1e30f;
                fj0[u] = 0;     fj1[u] = 0;     fj2[u] = 0;
            }
            for (int c = 0; c < NGRP; c += 4) {
                #pragma unroll
                for (int u = 0; u < 4; ++u) {
                    const float4 cc = scb[c + u];
                    if (redo) {
                        const int sidx = __float_as_int(cc.w);
                        const float ss = __fadd_rn(
                            __fadd_rn(__fmul_rn(cc.x, cc.x),
                                      __fmul_rn(cc.y, cc.y)),
                            __fmul_rn(cc.z, cc.z));
                        float acc = __fmul_rn(px, cc.x);
                        acc = fmaf(py, cc.y, acc);
                        acc = fmaf(pz, cc.z, acc);
                        const float dd = __fsub_rn(__fadd_rn(tn, ss),
                                                   __fmul_rn(2.0f, acc));
                        const bool lt2 = kvlt(dd, sidx, fe2[u], fj2[u]);
                        const bool lt1 = kvlt(dd, sidx, fe1[u], fj1[u]);
                        const bool lt0 = kvlt(dd, sidx, fe0[u], fj0[u]);
                        fe2[u] = lt1 ? fe1[u] : (lt2 ? dd : fe2[u]);
                        fj2[u] = lt1 ? fj1[u] : (lt2 ? sidx : fj2[u]);
                        fe1[u] = lt0 ? fe0[u] : (lt1 ? dd : fe1[u]);
                        fj1[u] = lt0 ? fj0[u] : (lt1 ? sidx : fj1[u]);
                        fe0[u] = lt0 ? dd : fe0[u];
                        fj0[u] = lt0 ? sidx : fj0[u];
                    }
                }
            }
            if (redo) {
                merge3(fe0[0], fj0[0], fe1[0], fj1[0], fe2[0], fj2[0],
                       fe0[1], fj0[1], fe1[1], fj1[1], fe2[1], fj2[1]);
                merge3(fe0[2], fj0[2], fe1[2], fj1[2], fe2[2], fj2[2],
                       fe0[3], fj0[3], fe1[3], fj1[3], fe2[3], fj2[3]);
                merge3(fe0[0], fj0[0], fe1[0], fj1[0], fe2[0], fj2[0],
                       fe0[2], fj0[2], fe1[2], fj1[2], fe2[2], fj2[2]);
                e0 = fe0[0]; e1 = fe1[0]; e2 = fe2[0];
                j0 = fj0[0]; j1 = fj1[0]; j2 = fj2[0];
            }
        }

        if (live) {
            const float f0 = fmaxf(e0, 1e-10f);
            const float f1 = fmaxf(e1, 1e-10f);
            const float f2 = fmaxf(e2, 1e-10f);
            const float r0 = 1.0f / f0, r1 = 1.0f / f1, r2 = 1.0f / f2;
            const float inv = 1.0f / __fadd_rn(__fadd_rn(r0, r1), r2);
            int2* pr = pairs_g + ((size_t)b * NPTS + pid) * 3;
            pr[0] = make_int2(j0, __float_as_int(r0 * inv));
            pr[1] = make_int2(j1, __float_as_int(r1 * inv));
            pr[2] = make_int2(j2, __float_as_int(r2 * inv));
        }
    }
}

// ===========================================================================
// Interp + 8x8 pool: round-6 B kernel verbatim (bit-identical), live cells
// only; dead region covered by memset.
// ===========================================================================
__global__ __launch_bounds__(192) void interp_pool_kernel(
    const float* __restrict__ feats,     // (B, G, DIM)
    const int2*  __restrict__ pairs_g,   // (B, N, 3)
    float* __restrict__ out)             // (B, DIM, 28, 28)
{
    const int cell = blockIdx.x;         // 0..391 (all live)
    const int b    = blockIdx.y;
    const int ho   = cell / HOUT;
    const int wo   = cell - ho * HOUT;
    const int t    = threadIdx.x;

    __shared__ int2 pairs[192];
    __shared__ __align__(16) float psum[4 * PSTRIDE];

    {
        const int p = t / 3;
        const int k = t - p * 3;
        const int n = (ho * KS + (p >> 3)) * IMG + wo * KS + (p & 7);
        pairs[t] = pairs_g[((size_t)b * NPTS + n) * 3 + k];
    }
    __syncthreads();

    {
        const int jslice = t / 48;
        const int dc     = t - jslice * 48;
        const int d0     = dc * 8;

        const float* fbase = feats + (size_t)b * NGRP * DIM + d0;
        float acc[8];
        #pragma unroll
        for (int dd = 0; dd < 8; ++dd) acc[dd] = 0.0f;

        const int jb = jslice * 48;
        #pragma unroll 4
        for (int jj = 0; jj < 48; ++jj) {
            const int2 pr = pairs[jb + jj];
            const float wg = __int_as_float(pr.y);
            const float4* fp = (const float4*)(fbase + (size_t)pr.x * DIM);
            const float4 f0 = fp[0];
            const float4 f1 = fp[1];
            acc[0] = fmaf(wg, f0.x, acc[0]);
            acc[1] = fmaf(wg, f0.y, acc[1]);
            acc[2] = fmaf(wg, f0.z, acc[2]);
            acc[3] = fmaf(wg, f0.w, acc[3]);
            acc[4] = fmaf(wg, f1.x, acc[4]);
            acc[5] = fmaf(wg, f1.y, acc[5]);
            acc[6] = fmaf(wg, f1.z, acc[6]);
            acc[7] = fmaf(wg, f1.w, acc[7]);
        }

        float4* pp = (float4*)&psum[jslice * PSTRIDE + d0];
        pp[0] = make_float4(acc[0], acc[1], acc[2], acc[3]);
        pp[1] = make_float4(acc[4], acc[5], acc[6], acc[7]);
    }
    __syncthreads();

    {
        const size_t obase = ((size_t)b * DIM) * (HOUT * HOUT) + (size_t)ho * HOUT + wo;
        const int da = t;
        const int db = t + 192;
        const float sa = __fadd_rn(__fadd_rn(__fadd_rn(psum[0 * PSTRIDE + da],
                                                       psum[1 * PSTRIDE + da]),
                                             psum[2 * PSTRIDE + da]),
                                   psum[3 * PSTRIDE + da]);
        const float sb = __fadd_rn(__fadd_rn(__fadd_rn(psum[0 * PSTRIDE + db],
                                                       psum[1 * PSTRIDE + db]),
                                             psum[2 * PSTRIDE + db]),
                                   psum[3 * PSTRIDE + db]);
        out[obase + (size_t)da * (HOUT * HOUT)] = sa * (1.0f / 64.0f);
        out[obase + (size_t)db * (HOUT * HOUT)] = sb * (1.0f / 64.0f);
    }
}

// ---------------------------------------------------------------------------
extern "C" void kernel_launch(void* const* d_in, const int* in_sizes, int n_in,
                              void* d_out, int out_size, void* d_ws, size_t ws_size,
                              hipStream_t stream) {
    const float* group_features  = (const float*)d_in[0];  // (B, G, DIM)
    const float* group_centers   = (const float*)d_in[1];  // (B, G, 3)
    const float* original_points = (const float*)d_in[2];  // (B, N, 3)

    float* out = (float*)d_out;                            // (B, DIM, 28, 28)
    char*  ws  = (char*)d_ws;
    int2*  pairs_g = (int2*)(ws + WS_PAIRS);

    hipMemsetAsync(out, 0, (size_t)out_size * sizeof(float), stream);

    {
        dim3 grid(NSLICE + 1, BATCH);                      // (9, 4)
        bin_kernel<<<grid, 512, 0, stream>>>(group_centers, original_points, ws);
    }
    {
        dim3 grid(NBIN / 4, BATCH);                        // wave per (batch, bin)
        nn_kernel<<<grid, 256, 0, stream>>>(ws, pairs_g);
    }
    {
        dim3 grid(LIVE_HO * HOUT, BATCH);                  // (392, 4) live cells
        interp_pool_kernel<<<grid, 192, 0, stream>>>(group_features, pairs_g, out);
    }
}

// Round 12
// 132.362 us; speedup vs baseline: 1.5549x; 1.5549x over previous
//
#include <hip/hip_runtime.h>

// Problem constants (B=4, G=512, Dim=384, N=25088, img 224, kernel_size 8)
#define BATCH 4
#define NGRP  512
#define DIM   384
#define NPTS  25088
#define IMG   224
#define KS    8
#define HOUT  28
#define LIVE_HO 14        // pooled rows 0..13 live, 14..27 exactly zero

#define GB    8
#define NBIN  (GB * GB * GB)       // 512
#define NSLICE 8
#define SLICE (NPTS / NSLICE)      // 3136 = 49 * 64 (blocks never straddle slices)
#define PSTRIDE 388                // psum row stride (floats)
#define RMAX  33                   // max padded partition row (ceil(512/16)|1)

// ---- workspace layout (bytes), per batch (R11 layout kept) ----
#define WS_CB 0                          // float4 cbin[512]        8192
#define WS_CS 8192                       // int cstart[513]
#define WS_PS 10256                      // int pstart[8][513] (unused by nn now)
#define WS_PB 26672                      // float4 pbin[25088]
#define WS_BSTRIDE 428080
#define WS_PAIRS (BATCH * WS_BSTRIDE)    // int2 pairs[B*N*3]

__device__ __forceinline__ bool kvlt(float da, int ia, float db, int ib) {
    // strict total order on (d2, center idx) — lax.top_k stable-tie semantics
    return (da < db) || ((da == db) && (ia < ib));
}

__device__ __forceinline__ void ins3(float dd, int sidx,
    float& e0, int& j0, float& e1, int& j1, float& e2, int& j2)
{
    const bool lt2 = kvlt(dd, sidx, e2, j2);
    const bool lt1 = kvlt(dd, sidx, e1, j1);
    const bool lt0 = kvlt(dd, sidx, e0, j0);
    e2 = lt1 ? e1 : (lt2 ? dd : e2);
    j2 = lt1 ? j1 : (lt2 ? sidx : j2);
    e1 = lt0 ? e0 : (lt1 ? dd : e1);
    j1 = lt0 ? j0 : (lt1 ? sidx : j1);
    e0 = lt0 ? dd : e0;
    j0 = lt0 ? sidx : j0;
}

// merge two sorted (d2,idx) triples -> sorted top-3 (proven R5-R7)
__device__ __forceinline__ void merge3(
    float& e0, int& j0, float& e1, int& j1, float& e2, int& j2,
    float f0, int g0, float f1, int g1, float f2, int g2)
{
    const bool c0 = kvlt(e0, j0, f0, g0);
    const float X0 = c0 ? e0 : f0;  const int U0 = c0 ? j0 : g0;
    const float X1 = c0 ? e1 : f1;  const int U1 = c0 ? j1 : g1;
    const float X2 = c0 ? e2 : f2;  const int U2 = c0 ? j2 : g2;
    const float Y0 = c0 ? f0 : e0;  const int V0 = c0 ? g0 : j0;
    const float Y1 = c0 ? f1 : e1;  const int V1 = c0 ? g1 : j1;
    const bool c1 = kvlt(X1, U1, Y0, V0);
    const float r1 = c1 ? X1 : Y0;  const int s1 = c1 ? U1 : V0;
    const bool c2a = kvlt(X2, U2, Y0, V0);
    const float r2a = c2a ? X2 : Y0; const int s2a = c2a ? U2 : V0;
    const bool c2b = kvlt(X1, U1, Y1, V1);
    const float r2b = c2b ? X1 : Y1; const int s2b = c2b ? U1 : V1;
    e0 = X0;  j0 = U0;
    e1 = r1;  j1 = s1;
    e2 = c1 ? r2a : r2b;
    j2 = c1 ? s2a : s2b;
}

__device__ __forceinline__ int bin_of(float v) {
    int i = (int)(v * 8.0f);             // *8 exact (pow2), inputs in [0,1)
    return min(max(i, 0), GB - 1);
}

// ===========================================================================
// Binning kernel (R11 verbatim): blockIdx.x==8 bins centers into an 8^3 CSR;
// ==s bins point slice s (slice-major pbin, bin-sorted within slice).
// Within-bin order nondeterministic — harmless: selection is (d2,idx)-lex
// order-invariant.
// ===========================================================================
__global__ __launch_bounds__(512) void bin_kernel(
    const float* __restrict__ centers,   // (B, G, 3)
    const float* __restrict__ points,    // (B, N, 3)
    char* __restrict__ ws)
{
    const int role = blockIdx.x;         // 0..7 point slices, 8 = centers
    const int b    = blockIdx.y;
    const int t    = threadIdx.x;

    __shared__ int cnt[NBIN];
    __shared__ int cur[NBIN];
    __shared__ int sstart[NBIN];
    __shared__ int wsum[8];

    cnt[t] = 0; cur[t] = 0;
    __syncthreads();

    char* wb = ws + (size_t)b * WS_BSTRIDE;

    if (role == NSLICE) {
        const float x = centers[((size_t)b * NGRP + t) * 3 + 0];
        const float y = centers[((size_t)b * NGRP + t) * 3 + 1];
        const float z = centers[((size_t)b * NGRP + t) * 3 + 2];
        const int bin = (bin_of(z) * GB + bin_of(y)) * GB + bin_of(x);
        atomicAdd(&cnt[bin], 1);
        __syncthreads();

        const int lane = t & 63, wid = t >> 6;
        const int v = cnt[t];
        int inc = v;
        #pragma unroll
        for (int d = 1; d < 64; d <<= 1) {
            const int nv = __shfl_up(inc, d, 64);
            if (lane >= d) inc += nv;
        }
        if (lane == 63) wsum[wid] = inc;
        __syncthreads();
        if (t == 0) {
            int acc = 0;
            #pragma unroll
            for (int i = 0; i < 8; ++i) { const int c = wsum[i]; wsum[i] = acc; acc += c; }
        }
        __syncthreads();
        const int startv = wsum[wid] + inc - v;

        float4* cb4 = (float4*)(wb + WS_CB);
        int*    cs  = (int*)(wb + WS_CS);
        cs[t] = startv;
        if (t == 0) cs[NBIN] = NGRP;
        sstart[t] = startv;
        __syncthreads();
        const int pos = sstart[bin] + atomicAdd(&cur[bin], 1);
        cb4[pos] = make_float4(x, y, z, __int_as_float(t));
    } else {
        const int n0 = role * SLICE;
        const float* pb = points + ((size_t)b * NPTS + n0) * 3;
        for (int n = t; n < SLICE; n += 512) {
            const float x = pb[n * 3 + 0];
            const float y = pb[n * 3 + 1];
            const float z = pb[n * 3 + 2];
            const int bin = (bin_of(z) * GB + bin_of(y)) * GB + bin_of(x);
            atomicAdd(&cnt[bin], 1);
        }
        __syncthreads();

        const int lane = t & 63, wid = t >> 6;
        const int v = cnt[t];
        int inc = v;
        #pragma unroll
        for (int d = 1; d < 64; d <<= 1) {
            const int nv = __shfl_up(inc, d, 64);
            if (lane >= d) inc += nv;
        }
        if (lane == 63) wsum[wid] = inc;
        __syncthreads();
        if (t == 0) {
            int acc = 0;
            #pragma unroll
            for (int i = 0; i < 8; ++i) { const int c = wsum[i]; wsum[i] = acc; acc += c; }
        }
        __syncthreads();
        const int startv = wsum[wid] + inc - v;

        int* ps = (int*)(wb + WS_PS) + role * (NBIN + 1);
        ps[t] = n0 + startv;
        if (t == 0) ps[NBIN] = n0 + SLICE;
        sstart[t] = startv;
        __syncthreads();

        float4* pb4 = (float4*)(wb + WS_PB);
        for (int n = t; n < SLICE; n += 512) {
            const float x = pb[n * 3 + 0];
            const float y = pb[n * 3 + 1];
            const float z = pb[n * 3 + 2];
            const int bin = (bin_of(z) * GB + bin_of(y)) * GB + bin_of(x);
            const int pos = n0 + sstart[bin] + atomicAdd(&cur[bin], 1);
            pb4[pos] = make_float4(x, y, z, __int_as_float(n0 + n));
        }
    }
}

// ===========================================================================
// NN kernel — R4's measured-fast shape (grid (392,4) x 256thr, 16-way
// partition split, 4 px/thread, butterfly merge) + grid pruning:
// block = 64 CONSECUTIVE bin-sorted points (pbin), its bins' +/-2 window
// (~125 centers) flattened into a padded LDS buffer; partitions scan padded
// rows (odd stride -> conflict-free). kvlt (d2,idx)-lex everywhere ->
// order-invariant -> bit-identical selection; per-pixel acceptance
// e2 < r_cov^2 - 1e-5 (r_cov = dist to real window faces, >= 0.25 by
// construction); failures do a masked full-512 rescan (exact).
// ===========================================================================
__global__ __launch_bounds__(256) void nn_kernel(
    const char* __restrict__ ws,
    int2* __restrict__ pairs_g)          // (B, N, 3) packed (idx, w bits)
{
    const int b = blockIdx.y;
    const int t = threadIdx.x;

    __shared__ float4 spts[64];                  // this block's 64 sorted points
    __shared__ int    scs[NBIN + 1];             // center CSR
    __shared__ float4 cand[16 * RMAX];           // padded partition rows
    __shared__ int    candi[16 * RMAX];
    __shared__ int    binfo[3];                  // ncand, L16, R

    const char* wb = ws + (size_t)b * WS_BSTRIDE;
    const float4* g4  = (const float4*)(wb + WS_CB);
    const int*    gs  = (const int*)(wb + WS_CS);
    const float4* pb4 = (const float4*)(wb + WS_PB);

    const int i0 = blockIdx.x * 64;              // 392*64 = 25088; slice-aligned
    if (t < 64) spts[t] = pb4[i0 + t];
    for (int i = t; i < NBIN + 1; i += 256) scs[i] = gs[i];
    __syncthreads();

    // ---- block-uniform window from first/last point's bin (sorted order) ----
    const float4 pA = spts[0];
    const float4 pB = spts[63];
    const int ax = bin_of(pA.x), ay = bin_of(pA.y), az = bin_of(pA.z);
    const int ex = bin_of(pB.x), ey = bin_of(pB.y), ez = bin_of(pB.z);
    int xlo, xhi, ylo, yhi;
    const int zlo = az, zhi = ez;
    if (az != ez)      { xlo = 0; xhi = 7; ylo = 0;  yhi = 7;  }
    else if (ay != ey) { xlo = 0; xhi = 7; ylo = ay; yhi = ey; }
    else               { xlo = ax; xhi = ex; ylo = ay; yhi = ay; }
    const int wx0 = max(xlo - 2, 0), wx1 = min(xhi + 2, 7);
    const int wy0 = max(ylo - 2, 0), wy1 = min(yhi + 2, 7);
    const int wz0 = max(zlo - 2, 0), wz1 = min(zhi + 2, 7);
    const int ny = wy1 - wy0 + 1;
    const int nrows = (wz1 - wz0 + 1) * ny;      // <= 64

    // ---- wave 0: row segments, prefix scan, publish sizes ----
    int segStart = 0, segLen = 0, dst = 0;
    if (t < 64) {
        const int lane = t;
        if (lane < nrows) {
            const int zz = wz0 + lane / ny;
            const int yy = wy0 + lane - (lane / ny) * ny;
            const int rowbase = (zz * GB + yy) * GB;
            segStart = scs[rowbase + wx0];
            segLen   = scs[rowbase + wx1 + 1] - segStart;
        }
        int pre = segLen;
        #pragma unroll
        for (int d = 1; d < 64; d <<= 1) {
            const int nv = __shfl_up(pre, d, 64);
            if (lane >= d) pre += nv;
        }
        dst = pre - segLen;
        if (lane == 0) {
            // total from an inclusive scan: broadcast from last row lane
        }
        const int ncand = __shfl(pre, nrows - 1, 64);
        if (lane == 0) {
            int L16 = (ncand + 15) >> 4;
            if (L16 < 1) L16 = 1;
            binfo[0] = ncand;
            binfo[1] = L16;
            binfo[2] = L16 | 1;                  // odd stride -> conflict-free
        }
    }
    __syncthreads();
    const int ncand = binfo[0];
    const int L16   = binfo[1];
    const int R     = binfo[2];

    // ---- sentinel-fill padded rows, then copy real candidates ----
    for (int i = t; i < 16 * R; i += 256) {
        cand[i]  = make_float4(0.0f, 0.0f, 0.0f, 1e30f);
        candi[i] = 0x7fffffff;
    }
    __syncthreads();
    if (t < 64 && t < nrows) {
        for (int k = 0; k < segLen; ++k) {
            const int f = dst + k;
            const int p = f / L16;               // partition
            const int slot = p * R + (f - p * L16);
            const float4 cc = g4[segStart + k];  // global, L2-hot
            const float ss = __fadd_rn(__fadd_rn(__fmul_rn(cc.x, cc.x),
                                                 __fmul_rn(cc.y, cc.y)),
                                       __fmul_rn(cc.z, cc.z));
            cand[slot]  = make_float4(cc.x, cc.y, cc.z, ss);
            candi[slot] = __float_as_int(cc.w);
        }
    }
    __syncthreads();

    // ---- hot phase: R4 structure (grp = 4 px, part = candidate partition) ----
    const int grp  = t >> 4;   // 0..15
    const int part = t & 15;   // 0..15

    float px[4], py[4], pz[4], tn[4];
    int   pid[4];
    #pragma unroll
    for (int q = 0; q < 4; ++q) {
        const float4 P = spts[grp * 4 + q];
        px[q] = P.x; py[q] = P.y; pz[q] = P.z;
        pid[q] = __float_as_int(P.w);
        tn[q] = __fadd_rn(__fadd_rn(__fmul_rn(P.x, P.x), __fmul_rn(P.y, P.y)),
                          __fmul_rn(P.z, P.z));
    }

    float e0[4], e1[4], e2[4];
    int   j0[4], j1[4], j2[4];
    #pragma unroll
    for (int q = 0; q < 4; ++q) {
        e0[q] = 1e30f; e1[q] = 1e30f; e2[q] = 1e30f;
        j0[q] = 0;     j1[q] = 0;     j2[q] = 0;
    }

    const int Lu = __builtin_amdgcn_readfirstlane(L16);
    const float4* cp = &cand[part * R];
    const int*    ci = &candi[part * R];
    for (int i = 0; i < Lu; ++i) {
        const float4 cc = cp[i];
        const int sidx  = ci[i];
        #pragma unroll
        for (int q = 0; q < 4; ++q) {
            float acc = __fmul_rn(px[q], cc.x);
            acc = fmaf(py[q], cc.y, acc);
            acc = fmaf(pz[q], cc.z, acc);
            const float dd = __fsub_rn(__fadd_rn(tn[q], cc.w),
                                       __fmul_rn(2.0f, acc));
            ins3(dd, sidx, e0[q], j0[q], e1[q], j1[q], e2[q], j2[q]);
        }
    }

    // ---- butterfly merge over the 16 partitions ----
    #pragma unroll
    for (int m = 1; m <= 8; m <<= 1) {
        #pragma unroll
        for (int q = 0; q < 4; ++q) {
            const float oa = __shfl_xor(e0[q], m, 64);
            const float ob = __shfl_xor(e1[q], m, 64);
            const float oc = __shfl_xor(e2[q], m, 64);
            const int   ya = __shfl_xor(j0[q], m, 64);
            const int   yb = __shfl_xor(j1[q], m, 64);
            const int   yc = __shfl_xor(j2[q], m, 64);
            merge3(e0[q], j0[q], e1[q], j1[q], e2[q], j2[q],
                   oa, ya, ob, yb, oc, yc);
        }
    }

    // ---- epilogue on part==0: acceptance, rare exact rescan, weights ----
    if (part == 0) {
        #pragma unroll
        for (int q = 0; q < 4; ++q) {
            float rc = 1e30f;
            if (wx0 > 0) rc = fminf(rc, px[q] - 0.125f * (float)wx0);
            if (wx1 < 7) rc = fminf(rc, 0.125f * (float)(wx1 + 1) - px[q]);
            if (wy0 > 0) rc = fminf(rc, py[q] - 0.125f * (float)wy0);
            if (wy1 < 7) rc = fminf(rc, 0.125f * (float)(wy1 + 1) - py[q]);
            if (wz0 > 0) rc = fminf(rc, pz[q] - 0.125f * (float)wz0);
            if (wz1 < 7) rc = fminf(rc, 0.125f * (float)(wz1 + 1) - pz[q]);
            const bool ok = (e2[q] < rc * rc - 1e-5f);

            if (!ok) {   // exact full rescan (rare), fresh state, ILP-4
                float a0[4], a1[4], a2[4];
                int   u0[4], u1[4], u2[4];
                #pragma unroll
                for (int u = 0; u < 4; ++u) {
                    a0[u] = 1e30f; a1[u] = 1e30f; a2[u] = 1e30f;
                    u0[u] = 0;     u1[u] = 0;     u2[u] = 0;
                }
                for (int c = 0; c < NGRP; c += 4) {
                    #pragma unroll
                    for (int u = 0; u < 4; ++u) {
                        const float4 cc = g4[c + u];
                        const int sidx = __float_as_int(cc.w);
                        const float ss = __fadd_rn(
                            __fadd_rn(__fmul_rn(cc.x, cc.x),
                                      __fmul_rn(cc.y, cc.y)),
                            __fmul_rn(cc.z, cc.z));
                        float acc = __fmul_rn(px[q], cc.x);
                        acc = fmaf(py[q], cc.y, acc);
                        acc = fmaf(pz[q], cc.z, acc);
                        const float dd = __fsub_rn(__fadd_rn(tn[q], ss),
                                                   __fmul_rn(2.0f, acc));
                        ins3(dd, sidx, a0[u], u0[u], a1[u], u1[u], a2[u], u2[u]);
                    }
                }
                merge3(a0[0], u0[0], a1[0], u1[0], a2[0], u2[0],
                       a0[1], u0[1], a1[1], u1[1], a2[1], u2[1]);
                merge3(a0[2], u0[2], a1[2], u1[2], a2[2], u2[2],
                       a0[3], u0[3], a1[3], u1[3], a2[3], u2[3]);
                merge3(a0[0], u0[0], a1[0], u1[0], a2[0], u2[0],
                       a0[2], u0[2], a1[2], u1[2], a2[2], u2[2]);
                e0[q] = a0[0]; e1[q] = a1[0]; e2[q] = a2[0];
                j0[q] = u0[0]; j1[q] = u1[0]; j2[q] = u2[0];
            }

            const float f0 = fmaxf(e0[q], 1e-10f);
            const float f1 = fmaxf(e1[q], 1e-10f);
            const float f2 = fmaxf(e2[q], 1e-10f);
            const float r0 = 1.0f / f0, r1 = 1.0f / f1, r2 = 1.0f / f2;
            const float inv = 1.0f / __fadd_rn(__fadd_rn(r0, r1), r2);
            int2* pr = pairs_g + ((size_t)b * NPTS + pid[q]) * 3;
            pr[0] = make_int2(j0[q], __float_as_int(r0 * inv));
            pr[1] = make_int2(j1[q], __float_as_int(r1 * inv));
            pr[2] = make_int2(j2[q], __float_as_int(r2 * inv));
        }
    }
}

// ===========================================================================
// Interp + 8x8 pool: round-6 B kernel verbatim (bit-identical), live cells
// only; dead region covered by memset.
// ===========================================================================
__global__ __launch_bounds__(192) void interp_pool_kernel(
    const float* __restrict__ feats,     // (B, G, DIM)
    const int2*  __restrict__ pairs_g,   // (B, N, 3)
    float* __restrict__ out)             // (B, DIM, 28, 28)
{
    const int cell = blockIdx.x;         // 0..391 (all live)
    const int b    = blockIdx.y;
    const int ho   = cell / HOUT;
    const int wo   = cell - ho * HOUT;
    const int t    = threadIdx.x;

    __shared__ int2 pairs[192];
    __shared__ __align__(16) float psum[4 * PSTRIDE];

    {
        const int p = t / 3;
        const int k = t - p * 3;
        const int n = (ho * KS + (p >> 3)) * IMG + wo * KS + (p & 7);
        pairs[t] = pairs_g[((size_t)b * NPTS + n) * 3 + k];
    }
    __syncthreads();

    {
        const int jslice = t / 48;
        const int dc     = t - jslice * 48;
        const int d0     = dc * 8;

        const float* fbase = feats + (size_t)b * NGRP * DIM + d0;
        float acc[8];
        #pragma unroll
        for (int dd = 0; dd < 8; ++dd) acc[dd] = 0.0f;

        const int jb = jslice * 48;
        #pragma unroll 4
        for (int jj = 0; jj < 48; ++jj) {
            const int2 pr = pairs[jb + jj];
            const float wg = __int_as_float(pr.y);
            const float4* fp = (const float4*)(fbase + (size_t)pr.x * DIM);
            const float4 f0 = fp[0];
            const float4 f1 = fp[1];
            acc[0] = fmaf(wg, f0.x, acc[0]);
            acc[1] = fmaf(wg, f0.y, acc[1]);
            acc[2] = fmaf(wg, f0.z, acc[2]);
            acc[3] = fmaf(wg, f0.w, acc[3]);
            acc[4] = fmaf(wg, f1.x, acc[4]);
            acc[5] = fmaf(wg, f1.y, acc[5]);
            acc[6] = fmaf(wg, f1.z, acc[6]);
            acc[7] = fmaf(wg, f1.w, acc[7]);
        }

        float4* pp = (float4*)&psum[jslice * PSTRIDE + d0];
        pp[0] = make_float4(acc[0], acc[1], acc[2], acc[3]);
        pp[1] = make_float4(acc[4], acc[5], acc[6], acc[7]);
    }
    __syncthreads();

    {
        const size_t obase = ((size_t)b * DIM) * (HOUT * HOUT) + (size_t)ho * HOUT + wo;
        const int da = t;
        const int db = t + 192;
        const float sa = __fadd_rn(__fadd_rn(__fadd_rn(psum[0 * PSTRIDE + da],
                                                       psum[1 * PSTRIDE + da]),
                                             psum[2 * PSTRIDE + da]),
                                   psum[3 * PSTRIDE + da]);
        const float sb = __fadd_rn(__fadd_rn(__fadd_rn(psum[0 * PSTRIDE + db],
                                                       psum[1 * PSTRIDE + db]),
                                             psum[2 * PSTRIDE + db]),
                                   psum[3 * PSTRIDE + db]);
        out[obase + (size_t)da * (HOUT * HOUT)] = sa * (1.0f / 64.0f);
        out[obase + (size_t)db * (HOUT * HOUT)] = sb * (1.0f / 64.0f);
    }
}

// ---------------------------------------------------------------------------
extern "C" void kernel_launch(void* const* d_in, const int* in_sizes, int n_in,
                              void* d_out, int out_size, void* d_ws, size_t ws_size,
                              hipStream_t stream) {
    const float* group_features  = (const float*)d_in[0];  // (B, G, DIM)
    const float* group_centers   = (const float*)d_in[1];  // (B, G, 3)
    const float* original_points = (const float*)d_in[2];  // (B, N, 3)

    float* out = (float*)d_out;                            // (B, DIM, 28, 28)
    char*  ws  = (char*)d_ws;
    int2*  pairs_g = (int2*)(ws + WS_PAIRS);

    hipMemsetAsync(out, 0, (size_t)out_size * sizeof(float), stream);

    {
        dim3 grid(NSLICE + 1, BATCH);                      // (9, 4)
        bin_kernel<<<grid, 512, 0, stream>>>(group_centers, original_points, ws);
    }
    {
        dim3 grid(NPTS / 64, BATCH);                       // (392, 4) = R4's shape
        nn_kernel<<<grid, 256, 0, stream>>>(ws, pairs_g);
    }
    {
        dim3 grid(LIVE_HO * HOUT, BATCH);                  // (392, 4) live cells
        interp_pool_kernel<<<grid, 192, 0, stream>>>(group_features, pairs_g, out);
    }
}